// Round 1
// baseline (336.738 us; speedup 1.0000x reference)
//
#include <hip/hip_runtime.h>
#include <math.h>

#define BATCH 4
#define CDIM 256
#define NDIM 4096
#define CLD 32
#define EPSBN 1e-5f

// XOR swizzle for [64][36] fp32 LDS tiles: spreads row-stride-36 (== 4 mod 32)
// across bank quads. Valid for scalar or float4-base column indices (bits 2..4).
#define SWZ(row, c) ((c) ^ ((((row) >> 3) & 7) << 2))

// ---------------- Kernel 1: QKV projection + BN + ReLU ----------------
// grid (N/64, B), block 256. Outputs q,k,v laid out [B][CL][N] in ws.
__global__ __launch_bounds__(256) void proj_qkv(
    const float* __restrict__ x,
    const float* __restrict__ w1, const float* __restrict__ w2, const float* __restrict__ w3,
    const float* __restrict__ b1s, const float* __restrict__ b1b, const float* __restrict__ b1m, const float* __restrict__ b1v,
    const float* __restrict__ b2s, const float* __restrict__ b2b, const float* __restrict__ b2m, const float* __restrict__ b2v,
    const float* __restrict__ b3s, const float* __restrict__ b3b, const float* __restrict__ b3m, const float* __restrict__ b3v,
    float* __restrict__ qo, float* __restrict__ ko, float* __restrict__ vo)
{
    __shared__ float wch[96][64];   // 24.5 KB chunk of combined [96][256] weight

    const int tid = threadIdx.x;
    const int nb  = blockIdx.y;
    const int n   = blockIdx.x * 64 + (tid & 63);
    const int g   = tid >> 6;       // 0..3 -> outputs g*24 .. g*24+23

    float acc[24];
#pragma unroll
    for (int o = 0; o < 24; ++o) acc[o] = 0.f;

    const float* xb = x + (size_t)nb * CDIM * NDIM + n;

    for (int c0 = 0; c0 < CDIM; c0 += 64) {
        __syncthreads();
        // stage 96x64 weight chunk (rows 0-31: w1, 32-63: w2, 64-95: w3)
        for (int t = tid; t < 1536; t += 256) {
            int row = t >> 4;
            int cc4 = (t & 15) << 2;
            const float* wsrc = (row < 32) ? w1 : ((row < 64) ? w2 : w3);
            float4 wv = *reinterpret_cast<const float4*>(wsrc + (size_t)(row & 31) * CDIM + c0 + cc4);
            *reinterpret_cast<float4*>(&wch[row][cc4]) = wv;
        }
        __syncthreads();
#pragma unroll 4
        for (int c4 = 0; c4 < 64; c4 += 4) {
            float x0 = xb[(size_t)(c0 + c4 + 0) * NDIM];
            float x1 = xb[(size_t)(c0 + c4 + 1) * NDIM];
            float x2 = xb[(size_t)(c0 + c4 + 2) * NDIM];
            float x3 = xb[(size_t)(c0 + c4 + 3) * NDIM];
#pragma unroll
            for (int o = 0; o < 24; ++o) {
                float4 wv = *reinterpret_cast<const float4*>(&wch[g * 24 + o][c4]);  // wave-uniform -> broadcast
                acc[o] = fmaf(wv.x, x0, acc[o]);
                acc[o] = fmaf(wv.y, x1, acc[o]);
                acc[o] = fmaf(wv.z, x2, acc[o]);
                acc[o] = fmaf(wv.w, x3, acc[o]);
            }
        }
    }

#pragma unroll
    for (int o = 0; o < 24; ++o) {
        int oo = g * 24 + o;
        int which = oo >> 5;      // 0:q 1:k 2:v  (compile-time per unrolled o)
        int cl = oo & 31;
        const float* ps = (which == 0) ? b1s : ((which == 1) ? b2s : b3s);
        const float* pb = (which == 0) ? b1b : ((which == 1) ? b2b : b3b);
        const float* pm = (which == 0) ? b1m : ((which == 1) ? b2m : b3m);
        const float* pv = (which == 0) ? b1v : ((which == 1) ? b2v : b3v);
        float inv = ps[cl] / sqrtf(pv[cl] + EPSBN);
        float y = (acc[o] - pm[cl]) * inv + pb[cl];
        y = fmaxf(y, 0.f);
        float* dst = (which == 0) ? qo : ((which == 1) ? ko : vo);
        dst[((size_t)nb * CLD + cl) * NDIM + n] = y;
    }
}

// ---------------- Kernel 2: flash attention ----------------
// grid (N/64, B), block 256. agg [B][CL][N].
__global__ __launch_bounds__(256) void flash_attn(
    const float* __restrict__ q, const float* __restrict__ k, const float* __restrict__ v,
    float* __restrict__ agg)
{
    __shared__ float Qt[64][36];
    __shared__ float Kt[64][36];
    __shared__ float Vt[64][36];
    __shared__ float S[64][66];     // scores -> p, float2 access (odd rows not 16B aligned)
    __shared__ float red[4][64];
    __shared__ float mrun[64], lrun[64], fac[64];

    const int tid = threadIdx.x;
    const int nb  = blockIdx.y;
    const int i0  = blockIdx.x * 64;

    // stage Q tile once (coalesced global, swizzled LDS)
    {
        int jl = tid & 63;
        int c0 = tid >> 6;
        const float* qb = q + (size_t)nb * CLD * NDIM + i0 + jl;
#pragma unroll
        for (int cc = 0; cc < CLD; cc += 4) {
            int c = cc + c0;
            Qt[jl][SWZ(jl, c)] = qb[(size_t)c * NDIM];
        }
    }
    if (tid < 64) { mrun[tid] = -1e30f; lrun[tid] = 0.f; }

    // PV mapping: rows (ig, ig+32), col quad cg*4
    const int ig = tid & 31;
    const int cg = tid >> 5;        // 0..7
    // QK mapping: rows iq+16r (r=0..3), cols jq*4+s (s=0..3)
    const int iq = tid & 15;
    const int jq = tid >> 4;        // 0..15

    float oacc0[4] = {0.f, 0.f, 0.f, 0.f};
    float oacc1[4] = {0.f, 0.f, 0.f, 0.f};

    for (int j0 = 0; j0 < NDIM; j0 += 64) {
        __syncthreads();                                   // A: prev tile fully consumed
        {
            int jl = tid & 63;
            int c0 = tid >> 6;
            const float* kb = k + (size_t)nb * CLD * NDIM + j0 + jl;
            const float* vb = v + (size_t)nb * CLD * NDIM + j0 + jl;
#pragma unroll
            for (int cc = 0; cc < CLD; cc += 4) {
                int c = cc + c0;
                Kt[jl][SWZ(jl, c)] = kb[(size_t)c * NDIM];
                Vt[jl][SWZ(jl, c)] = vb[(size_t)c * NDIM];
            }
        }
        __syncthreads();                                   // B: K/V staged

        // ---- QK^T: 4x4 register block per thread ----
        float sacc[4][4];
#pragma unroll
        for (int r = 0; r < 4; ++r)
#pragma unroll
            for (int s = 0; s < 4; ++s) sacc[r][s] = 0.f;

#pragma unroll 2
        for (int c4 = 0; c4 < CLD; c4 += 4) {
            float4 qv[4], kv[4];
#pragma unroll
            for (int r = 0; r < 4; ++r) {
                int row = iq + 16 * r;
                qv[r] = *reinterpret_cast<const float4*>(&Qt[row][SWZ(row, c4)]);
            }
#pragma unroll
            for (int s = 0; s < 4; ++s) {
                int row = jq * 4 + s;
                kv[s] = *reinterpret_cast<const float4*>(&Kt[row][SWZ(row, c4)]);
            }
#pragma unroll
            for (int r = 0; r < 4; ++r)
#pragma unroll
                for (int s = 0; s < 4; ++s) {
                    sacc[r][s] = fmaf(qv[r].x, kv[s].x, sacc[r][s]);
                    sacc[r][s] = fmaf(qv[r].y, kv[s].y, sacc[r][s]);
                    sacc[r][s] = fmaf(qv[r].z, kv[s].z, sacc[r][s]);
                    sacc[r][s] = fmaf(qv[r].w, kv[s].w, sacc[r][s]);
                }
        }
#pragma unroll
        for (int r = 0; r < 4; ++r) {
            *reinterpret_cast<float2*>(&S[iq + 16 * r][jq * 4])     = make_float2(sacc[r][0], sacc[r][1]);
            *reinterpret_cast<float2*>(&S[iq + 16 * r][jq * 4 + 2]) = make_float2(sacc[r][2], sacc[r][3]);
        }
        __syncthreads();                                   // C: S complete

        // ---- online softmax: thread (i = tid&63, qd = tid>>6) owns 16 cols ----
        {
            const int i  = tid & 63;
            const int qd = tid >> 6;
            float2 sv[8];
            float mloc = -1e30f;
#pragma unroll
            for (int t = 0; t < 8; ++t) {
                sv[t] = *reinterpret_cast<const float2*>(&S[i][qd * 16 + t * 2]);
                mloc = fmaxf(mloc, fmaxf(sv[t].x, sv[t].y));
            }
            red[qd][i] = mloc;
            __syncthreads();                               // D: maxima ready
            float mtile = fmaxf(fmaxf(red[0][i], red[1][i]), fmaxf(red[2][i], red[3][i]));
            float mold  = mrun[i];
            float mnew  = fmaxf(mold, mtile);
            float f     = __expf(mold - mnew);
            float ssum  = 0.f;
#pragma unroll
            for (int t = 0; t < 8; ++t) {
                float2 p2 = make_float2(__expf(sv[t].x - mnew), __expf(sv[t].y - mnew));
                ssum += p2.x + p2.y;
                *reinterpret_cast<float2*>(&S[i][qd * 16 + t * 2]) = p2;
            }
            __syncthreads();                               // E: max-reads of red done
            red[qd][i] = ssum;
            __syncthreads();                               // F: sums ready
            if (qd == 0) {
                float stile = red[0][i] + red[1][i] + red[2][i] + red[3][i];
                lrun[i] = lrun[i] * f + stile;
                mrun[i] = mnew;
                fac[i]  = f;
            }
        }
        __syncthreads();                                   // G: fac/l/m published

        // ---- PV: rows (ig, ig+32) x cols cg*4..+3 ----
        {
            float f0 = fac[ig];
            float f1 = fac[ig + 32];
#pragma unroll
            for (int cc = 0; cc < 4; ++cc) { oacc0[cc] *= f0; oacc1[cc] *= f1; }
#pragma unroll 2
            for (int j = 0; j < 64; j += 4) {
                float2 pa0 = *reinterpret_cast<const float2*>(&S[ig][j]);
                float2 pa1 = *reinterpret_cast<const float2*>(&S[ig][j + 2]);
                float2 pb0 = *reinterpret_cast<const float2*>(&S[ig + 32][j]);
                float2 pb1 = *reinterpret_cast<const float2*>(&S[ig + 32][j + 2]);
                float pav[4] = {pa0.x, pa0.y, pa1.x, pa1.y};
                float pbv[4] = {pb0.x, pb0.y, pb1.x, pb1.y};
#pragma unroll
                for (int jj = 0; jj < 4; ++jj) {
                    int row = j + jj;
                    float4 vv = *reinterpret_cast<const float4*>(&Vt[row][SWZ(row, cg * 4)]);
                    oacc0[0] = fmaf(pav[jj], vv.x, oacc0[0]);
                    oacc0[1] = fmaf(pav[jj], vv.y, oacc0[1]);
                    oacc0[2] = fmaf(pav[jj], vv.z, oacc0[2]);
                    oacc0[3] = fmaf(pav[jj], vv.w, oacc0[3]);
                    oacc1[0] = fmaf(pbv[jj], vv.x, oacc1[0]);
                    oacc1[1] = fmaf(pbv[jj], vv.y, oacc1[1]);
                    oacc1[2] = fmaf(pbv[jj], vv.z, oacc1[2]);
                    oacc1[3] = fmaf(pbv[jj], vv.w, oacc1[3]);
                }
            }
        }
    }

    // finalize: divide by l, write agg[b][c][n]
    {
        float li0 = 1.0f / lrun[ig];
        float li1 = 1.0f / lrun[ig + 32];
        float* ab = agg + ((size_t)nb * CLD + cg * 4) * NDIM + i0;
#pragma unroll
        for (int cc = 0; cc < 4; ++cc) {
            ab[(size_t)cc * NDIM + ig]      = oacc0[cc] * li0;
            ab[(size_t)cc * NDIM + ig + 32] = oacc1[cc] * li1;
        }
    }
}

// ---------------- Kernel 3: output projection + BN4 + ReLU + residual ----------------
// grid (N/64, B), block 256. thread: n = tid&63, o-range (tid>>6)*64..+63
__global__ __launch_bounds__(256) void out_proj(
    const float* __restrict__ agg, const float* __restrict__ wo,
    const float* __restrict__ b4s, const float* __restrict__ b4b,
    const float* __restrict__ b4m, const float* __restrict__ b4v,
    const float* __restrict__ x, const float* __restrict__ gamma,
    float* __restrict__ out)
{
    __shared__ float wsh[256][32];   // 32 KB
    __shared__ float sc[256], bi[256];

    const int tid = threadIdx.x;
    const int nb  = blockIdx.y;
    const int n   = blockIdx.x * 64 + (tid & 63);
    const int og  = tid >> 6;

    for (int t = tid; t < 2048; t += 256) {
        int o = t >> 3, c4 = (t & 7) << 2;
        *reinterpret_cast<float4*>(&wsh[o][c4]) =
            *reinterpret_cast<const float4*>(wo + (size_t)o * CLD + c4);
    }
    {
        float inv = b4s[tid] / sqrtf(b4v[tid] + EPSBN);
        sc[tid] = inv;
        bi[tid] = b4b[tid] - b4m[tid] * inv;
    }
    __syncthreads();

    float av[32];
#pragma unroll
    for (int c = 0; c < 32; ++c)
        av[c] = agg[((size_t)nb * CLD + c) * NDIM + n];

    const float gm = gamma[0];
    const size_t base = (size_t)nb * CDIM * NDIM + n;
#pragma unroll 4
    for (int o0 = 0; o0 < 64; ++o0) {
        int o = og * 64 + o0;
        float acc = 0.f;
#pragma unroll
        for (int c4 = 0; c4 < 32; c4 += 4) {
            float4 wv = *reinterpret_cast<const float4*>(&wsh[o][c4]);   // broadcast
            acc = fmaf(wv.x, av[c4 + 0], acc);
            acc = fmaf(wv.y, av[c4 + 1], acc);
            acc = fmaf(wv.z, av[c4 + 2], acc);
            acc = fmaf(wv.w, av[c4 + 3], acc);
        }
        float y = fmaxf(fmaf(acc, sc[o], bi[o]), 0.f);
        out[base + (size_t)o * NDIM] = fmaf(gm, y, x[base + (size_t)o * NDIM]);
    }
}

extern "C" void kernel_launch(void* const* d_in, const int* in_sizes, int n_in,
                              void* d_out, int out_size, void* d_ws, size_t ws_size,
                              hipStream_t stream) {
    const float* x   = (const float*)d_in[0];
    const float* w1  = (const float*)d_in[1];
    const float* w2  = (const float*)d_in[2];
    const float* w3  = (const float*)d_in[3];
    const float* wo  = (const float*)d_in[4];
    const float* b1s = (const float*)d_in[5];
    const float* b1b = (const float*)d_in[6];
    const float* b1m = (const float*)d_in[7];
    const float* b1v = (const float*)d_in[8];
    const float* b2s = (const float*)d_in[9];
    const float* b2b = (const float*)d_in[10];
    const float* b2m = (const float*)d_in[11];
    const float* b2v = (const float*)d_in[12];
    const float* b3s = (const float*)d_in[13];
    const float* b3b = (const float*)d_in[14];
    const float* b3m = (const float*)d_in[15];
    const float* b3v = (const float*)d_in[16];
    const float* b4s = (const float*)d_in[17];
    const float* b4b = (const float*)d_in[18];
    const float* b4m = (const float*)d_in[19];
    const float* b4v = (const float*)d_in[20];
    const float* gm  = (const float*)d_in[21];
    float* out = (float*)d_out;

    float* ws = (float*)d_ws;
    const size_t seg = (size_t)BATCH * CLD * NDIM;   // 524288 floats
    float* q   = ws;
    float* k   = ws + seg;
    float* v   = ws + 2 * seg;
    float* agg = ws + 3 * seg;

    dim3 grid(NDIM / 64, BATCH);

    proj_qkv<<<grid, 256, 0, stream>>>(x, w1, w2, w3,
                                       b1s, b1b, b1m, b1v,
                                       b2s, b2b, b2m, b2v,
                                       b3s, b3b, b3m, b3v,
                                       q, k, v);
    flash_attn<<<grid, 256, 0, stream>>>(q, k, v, agg);
    out_proj<<<grid, 256, 0, stream>>>(agg, wo, b4s, b4b, b4m, b4v, x, gm, out);
}

// Round 2
// 124.627 us; speedup vs baseline: 2.7020x; 2.7020x over previous
//
#include <hip/hip_runtime.h>
#include <hip/hip_bf16.h>
#include <math.h>

#define BATCH 4
#define CDIM 256
#define NDIM 4096
#define CLD 32
#define EPSBN 1e-5f
#define NSPLIT 4
#define KEYS_PER_SPLIT (NDIM / NSPLIT)

typedef unsigned short u16;
typedef unsigned int u32;
typedef __attribute__((ext_vector_type(8))) short bf16x8;   // 8 bf16 = 4 VGPR MFMA operand
typedef __attribute__((ext_vector_type(16))) float f32x16;  // 32x32 MFMA accumulator
typedef __attribute__((ext_vector_type(4))) u32 u32x4;

__device__ inline u16 f2bf(float x) {
    return __builtin_bit_cast(u16, __float2bfloat16(x));
}
__device__ inline u32 pack_bf16x2(float a, float b) {
    return (u32)f2bf(a) | ((u32)f2bf(b) << 16);
}

// ---------------- Kernel 1: QKV projection + BN + ReLU -> bf16 ----------------
// grid (N/64, B, 2), block 256. q,k -> [B][N][32] bf16 ; v -> [B][32][N] bf16.
// Weights read via wave-uniform scalar loads (no LDS, no barriers).
__global__ __launch_bounds__(256) void proj_qkv(
    const float* __restrict__ x,
    const float* __restrict__ w1, const float* __restrict__ w2, const float* __restrict__ w3,
    const float* __restrict__ b1s, const float* __restrict__ b1b, const float* __restrict__ b1m, const float* __restrict__ b1v,
    const float* __restrict__ b2s, const float* __restrict__ b2b, const float* __restrict__ b2m, const float* __restrict__ b2v,
    const float* __restrict__ b3s, const float* __restrict__ b3b, const float* __restrict__ b3m, const float* __restrict__ b3v,
    u16* __restrict__ qo, u16* __restrict__ ko, u16* __restrict__ vo)
{
    const int tid = threadIdx.x;
    const int nb  = blockIdx.y;
    const int zh  = blockIdx.z;                                   // channel half
    const int n   = blockIdx.x * 64 + (tid & 63);
    const int g   = __builtin_amdgcn_readfirstlane(tid >> 6);     // wave-uniform 0..3
    const int o0  = zh * 48 + g * 12;                             // 12 channels of 96

    const float* wrows[12];
#pragma unroll
    for (int o = 0; o < 12; ++o) {
        int oo = o0 + o;
        const float* wsel = (oo < 32) ? w1 : ((oo < 64) ? w2 : w3);
        wrows[o] = wsel + (size_t)(oo & 31) * CDIM;
    }

    float acc[12];
#pragma unroll
    for (int o = 0; o < 12; ++o) acc[o] = 0.f;

    const float* xb = x + (size_t)nb * CDIM * NDIM + n;
#pragma unroll 4
    for (int c = 0; c < CDIM; c += 4) {
        float x0 = xb[(size_t)(c + 0) * NDIM];
        float x1 = xb[(size_t)(c + 1) * NDIM];
        float x2 = xb[(size_t)(c + 2) * NDIM];
        float x3 = xb[(size_t)(c + 3) * NDIM];
#pragma unroll
        for (int o = 0; o < 12; ++o) {
            float4 wv = *reinterpret_cast<const float4*>(wrows[o] + c);  // uniform -> s_load
            acc[o] = fmaf(wv.x, x0, acc[o]);
            acc[o] = fmaf(wv.y, x1, acc[o]);
            acc[o] = fmaf(wv.z, x2, acc[o]);
            acc[o] = fmaf(wv.w, x3, acc[o]);
        }
    }

#pragma unroll
    for (int o = 0; o < 12; o += 2) {
        int oo = o0 + o;
        int cl = oo & 31;
        const float *ps, *pb, *pm, *pv;
        if (oo < 32)      { ps = b1s; pb = b1b; pm = b1m; pv = b1v; }
        else if (oo < 64) { ps = b2s; pb = b2b; pm = b2m; pv = b2v; }
        else              { ps = b3s; pb = b3b; pm = b3m; pv = b3v; }
        float inv0 = ps[cl]     / sqrtf(pv[cl]     + EPSBN);
        float inv1 = ps[cl + 1] / sqrtf(pv[cl + 1] + EPSBN);
        float y0 = fmaxf((acc[o]     - pm[cl])     * inv0 + pb[cl],     0.f);
        float y1 = fmaxf((acc[o + 1] - pm[cl + 1]) * inv1 + pb[cl + 1], 0.f);
        u32 pk = pack_bf16x2(y0, y1);
        if (oo < 32) {
            *reinterpret_cast<u32*>(qo + ((size_t)nb * NDIM + n) * CLD + cl) = pk;
        } else if (oo < 64) {
            *reinterpret_cast<u32*>(ko + ((size_t)nb * NDIM + n) * CLD + cl) = pk;
        } else {
            vo[((size_t)nb * CLD + cl)     * NDIM + n] = (u16)(pk & 0xffffu);
            vo[((size_t)nb * CLD + cl + 1) * NDIM + n] = (u16)(pk >> 16);
        }
    }
}

// ---------------- Kernel 2: MFMA flash attention with KV split ----------------
// grid (N/128, B, NSPLIT), block 256 = 4 independent waves; wave owns 32 queries.
// S^T = K*Q^T  (D: col=lane&31=query, row=key=(r&3)+8*(r>>2)+4*hi)
// O^T = V^T*P^T (D: col=query, row=d)
// Partials: pO bf16 [S][B][32][N] (unnormalized), pM/pL f32 [S][B][N].
__global__ __launch_bounds__(256) void attn_mfma(
    const u16* __restrict__ q, const u16* __restrict__ k, const u16* __restrict__ v,
    u16* __restrict__ pO, float* __restrict__ pM, float* __restrict__ pL)
{
    const int tid  = threadIdx.x;
    const int lane = tid & 63;
    const int w    = tid >> 6;
    const int b    = blockIdx.y;
    const int s    = blockIdx.z;
    const int q0   = (blockIdx.x * 4 + w) * 32;
    const int col  = lane & 31;
    const int hi   = lane >> 5;

    // Q fragments (B-operand: col=query, k=d=8*hi+i (+16 for frag1)) — held all loop
    const u16* qp = q + ((size_t)b * NDIM + q0 + col) * CLD + 8 * hi;
    bf16x8 qf0 = *reinterpret_cast<const bf16x8*>(qp);
    bf16x8 qf1 = *reinterpret_cast<const bf16x8*>(qp + 16);

    f32x16 o = {0.f,0.f,0.f,0.f, 0.f,0.f,0.f,0.f, 0.f,0.f,0.f,0.f, 0.f,0.f,0.f,0.f};
    float m_run = -3e38f, l_run = 0.f;

    const int kstart = s * KEYS_PER_SPLIT;
    const u16* kb = k + (size_t)b * NDIM * CLD;
    const u16* vb = v + (size_t)b * CLD * NDIM + (size_t)col * NDIM;

    for (int kt = 0; kt < KEYS_PER_SPLIT; kt += 32) {
        const int k0 = kstart + kt;
        // K frags (A-operand: row=key=col, k=d)
        const u16* kp = kb + (size_t)(k0 + col) * CLD + 8 * hi;
        bf16x8 kf0 = *reinterpret_cast<const bf16x8*>(kp);
        bf16x8 kf1 = *reinterpret_cast<const bf16x8*>(kp + 16);
        // V frags (A-operand of PV: row=d=col, k=key offset 8*hi+i)
        const u16* vp = vb + k0 + 8 * hi;
        bf16x8 vf0 = *reinterpret_cast<const bf16x8*>(vp);
        bf16x8 vf1 = *reinterpret_cast<const bf16x8*>(vp + 16);

        f32x16 sa = {0.f,0.f,0.f,0.f, 0.f,0.f,0.f,0.f, 0.f,0.f,0.f,0.f, 0.f,0.f,0.f,0.f};
        sa = __builtin_amdgcn_mfma_f32_32x32x16_bf16(kf0, qf0, sa, 0, 0, 0);
        sa = __builtin_amdgcn_mfma_f32_32x32x16_bf16(kf1, qf1, sa, 0, 0, 0);
        // sa[r] = S[q0+col][k0 + (r&3)+8*(r>>2)+4*hi]

        // ---- online softmax (lane-local row; one cross-half shuffle) ----
        float tmax = sa[0];
#pragma unroll
        for (int r = 1; r < 16; ++r) tmax = fmaxf(tmax, sa[r]);
        tmax = fmaxf(tmax, __shfl_xor(tmax, 32));
        float mnew = fmaxf(m_run, tmax);
        float f = __expf(m_run - mnew);
        float p[16];
        float psum = 0.f;
#pragma unroll
        for (int r = 0; r < 16; ++r) { p[r] = __expf(sa[r] - mnew); psum += p[r]; }
        psum += __shfl_xor(psum, 32);
        l_run = l_run * f + psum;
        m_run = mnew;
#pragma unroll
        for (int r = 0; r < 16; ++r) o[r] *= f;

        // ---- P -> bf16, redistribute to PV B-fragment layout ----
        // lane holds keys {(r&3)+8*(r>>2)+4*hi}; B-frag needs keys 16m+8*hi+i (i=0..7).
        u32 bw[8], bx[8];
#pragma unroll
        for (int t = 0; t < 8; ++t) bw[t] = pack_bf16x2(p[2 * t], p[2 * t + 1]);
#pragma unroll
        for (int t = 0; t < 8; ++t) bx[t] = (u32)__shfl_xor((int)bw[t], 32);

        u32x4 f0u, f1u;
        f0u.x = hi ? bx[2] : bw[0];  f0u.y = hi ? bx[3] : bw[1];
        f0u.z = hi ? bw[2] : bx[0];  f0u.w = hi ? bw[3] : bx[1];
        f1u.x = hi ? bx[6] : bw[4];  f1u.y = hi ? bx[7] : bw[5];
        f1u.z = hi ? bw[6] : bx[4];  f1u.w = hi ? bw[7] : bx[5];
        bf16x8 pf0 = __builtin_bit_cast(bf16x8, f0u);
        bf16x8 pf1 = __builtin_bit_cast(bf16x8, f1u);

        o = __builtin_amdgcn_mfma_f32_32x32x16_bf16(vf0, pf0, o, 0, 0, 0);
        o = __builtin_amdgcn_mfma_f32_32x32x16_bf16(vf1, pf1, o, 0, 0, 0);
    }

    // store unnormalized partial O (bf16) + m,l
    u16* Ob = pO + ((size_t)s * BATCH + b) * CLD * NDIM + q0;
#pragma unroll
    for (int r = 0; r < 16; ++r) {
        int d = (r & 3) + 8 * (r >> 2) + 4 * hi;
        Ob[(size_t)d * NDIM + col] = f2bf(o[r]);
    }
    if (hi == 0) {
        size_t mi = ((size_t)s * BATCH + b) * NDIM + q0 + col;
        pM[mi] = m_run;
        pL[mi] = l_run;
    }
}

// ---------------- Kernel 3: combine KV-split partials -> agg f32 [B][32][N] ----------------
__global__ __launch_bounds__(256) void combine(
    const u16* __restrict__ pO, const float* __restrict__ pM, const float* __restrict__ pL,
    float* __restrict__ agg)
{
    const int b = blockIdx.y;
    const int n = blockIdx.x * 256 + threadIdx.x;

    float m[NSPLIT], wgt[NSPLIT];
    float mstar = -3e38f;
#pragma unroll
    for (int s = 0; s < NSPLIT; ++s) {
        m[s] = pM[((size_t)s * BATCH + b) * NDIM + n];
        mstar = fmaxf(mstar, m[s]);
    }
    float denom = 0.f;
#pragma unroll
    for (int s = 0; s < NSPLIT; ++s) {
        wgt[s] = __expf(m[s] - mstar);
        denom += wgt[s] * pL[((size_t)s * BATCH + b) * NDIM + n];
    }
    float inv = 1.f / denom;
#pragma unroll 4
    for (int d = 0; d < CLD; ++d) {
        float a2 = 0.f;
#pragma unroll
        for (int s = 0; s < NSPLIT; ++s) {
            u32 u = pO[(((size_t)s * BATCH + b) * CLD + d) * NDIM + n];
            a2 = fmaf(wgt[s], __builtin_bit_cast(float, u << 16), a2);
        }
        agg[((size_t)b * CLD + d) * NDIM + n] = a2 * inv;
    }
}

// ---------------- Kernel 4: output projection + BN4 + ReLU + residual ----------------
__global__ __launch_bounds__(256) void out_proj(
    const float* __restrict__ agg, const float* __restrict__ wo,
    const float* __restrict__ b4s, const float* __restrict__ b4b,
    const float* __restrict__ b4m, const float* __restrict__ b4v,
    const float* __restrict__ x, const float* __restrict__ gamma,
    float* __restrict__ out)
{
    __shared__ float wsh[256][32];
    __shared__ float sc[256], bi[256];

    const int tid = threadIdx.x;
    const int nb  = blockIdx.y;
    const int n   = blockIdx.x * 64 + (tid & 63);
    const int og  = tid >> 6;

    for (int t = tid; t < 2048; t += 256) {
        int oo = t >> 3, c4 = (t & 7) << 2;
        *reinterpret_cast<float4*>(&wsh[oo][c4]) =
            *reinterpret_cast<const float4*>(wo + (size_t)oo * CLD + c4);
    }
    {
        float inv = b4s[tid] / sqrtf(b4v[tid] + EPSBN);
        sc[tid] = inv;
        bi[tid] = b4b[tid] - b4m[tid] * inv;
    }
    __syncthreads();

    float av[32];
#pragma unroll
    for (int c = 0; c < 32; ++c)
        av[c] = agg[((size_t)nb * CLD + c) * NDIM + n];

    const float gm = gamma[0];
    const size_t base = (size_t)nb * CDIM * NDIM + n;
#pragma unroll 4
    for (int o0 = 0; o0 < 64; ++o0) {
        int oo = og * 64 + o0;
        float acc = 0.f;
#pragma unroll
        for (int c4 = 0; c4 < 32; c4 += 4) {
            float4 wv = *reinterpret_cast<const float4*>(&wsh[oo][c4]);
            acc = fmaf(wv.x, av[c4 + 0], acc);
            acc = fmaf(wv.y, av[c4 + 1], acc);
            acc = fmaf(wv.z, av[c4 + 2], acc);
            acc = fmaf(wv.w, av[c4 + 3], acc);
        }
        float y = fmaxf(fmaf(acc, sc[oo], bi[oo]), 0.f);
        out[base + (size_t)oo * NDIM] = fmaf(gm, y, x[base + (size_t)oo * NDIM]);
    }
}

extern "C" void kernel_launch(void* const* d_in, const int* in_sizes, int n_in,
                              void* d_out, int out_size, void* d_ws, size_t ws_size,
                              hipStream_t stream) {
    const float* x   = (const float*)d_in[0];
    const float* w1  = (const float*)d_in[1];
    const float* w2  = (const float*)d_in[2];
    const float* w3  = (const float*)d_in[3];
    const float* wo  = (const float*)d_in[4];
    const float* b1s = (const float*)d_in[5];
    const float* b1b = (const float*)d_in[6];
    const float* b1m = (const float*)d_in[7];
    const float* b1v = (const float*)d_in[8];
    const float* b2s = (const float*)d_in[9];
    const float* b2b = (const float*)d_in[10];
    const float* b2m = (const float*)d_in[11];
    const float* b2v = (const float*)d_in[12];
    const float* b3s = (const float*)d_in[13];
    const float* b3b = (const float*)d_in[14];
    const float* b3m = (const float*)d_in[15];
    const float* b3v = (const float*)d_in[16];
    const float* b4s = (const float*)d_in[17];
    const float* b4b = (const float*)d_in[18];
    const float* b4m = (const float*)d_in[19];
    const float* b4v = (const float*)d_in[20];
    const float* gm  = (const float*)d_in[21];
    float* out = (float*)d_out;

    // ws layout (bytes):
    //   [0, 2MB)        : agg f32 [B][32][N]   (overlays qbf+kbf, which are dead by then)
    //   [0, 1MB)        : qbf bf16 [B][N][32]
    //   [1MB, 2MB)      : kbf bf16 [B][N][32]
    //   [2MB, 3MB)      : vbf bf16 [B][32][N]
    //   [3MB, 7MB)      : pO  bf16 [S][B][32][N]
    //   [7MB, 7.25MB)   : pM  f32  [S][B][N]
    //   [7.25MB, 7.5MB) : pL  f32  [S][B][N]
    char* W = (char*)d_ws;
    float* agg = (float*)W;
    u16* qbf = (u16*)W;
    u16* kbf = (u16*)(W + (1u << 20));
    u16* vbf = (u16*)(W + (2u << 20));
    u16* pO  = (u16*)(W + (3u << 20));
    float* pM = (float*)(W + (7u << 20));
    float* pL = (float*)(W + (7u << 20) + (1u << 18));

    dim3 gp(NDIM / 64, BATCH, 2);
    proj_qkv<<<gp, 256, 0, stream>>>(x, w1, w2, w3,
                                     b1s, b1b, b1m, b1v,
                                     b2s, b2b, b2m, b2v,
                                     b3s, b3b, b3m, b3v,
                                     qbf, kbf, vbf);

    dim3 ga(NDIM / 128, BATCH, NSPLIT);
    attn_mfma<<<ga, 256, 0, stream>>>(qbf, kbf, vbf, pO, pM, pL);

    combine<<<dim3(NDIM / 256, BATCH), 256, 0, stream>>>(pO, pM, pL, agg);

    out_proj<<<dim3(NDIM / 64, BATCH), 256, 0, stream>>>(agg, wo, b4s, b4b, b4m, b4v, x, gm, out);
}

// Round 3
// 78.772 us; speedup vs baseline: 4.2749x; 1.5821x over previous
//
#include <hip/hip_runtime.h>
#include <hip/hip_bf16.h>
#include <math.h>

#define BATCH 4
#define CDIM 256
#define NDIM 4096
#define CLD 32
#define EPSBN 1e-5f
#define NSPLIT 4
#define KEYS_PER_SPLIT (NDIM / NSPLIT)

typedef unsigned short u16;
typedef unsigned int u32;
typedef __attribute__((ext_vector_type(8))) short bf16x8;   // 8 bf16 = 4 VGPR MFMA operand
typedef __attribute__((ext_vector_type(16))) float f32x16;  // 32x32 MFMA accumulator
typedef __attribute__((ext_vector_type(4))) u32 u32x4;

__device__ inline u16 f2bf(float x) {
    return __builtin_bit_cast(u16, __float2bfloat16(x));
}
__device__ inline u32 pack_bf16x2(float a, float b) {
    return (u32)f2bf(a) | ((u32)f2bf(b) << 16);
}
__device__ inline float bfbits2f(u16 u) {
    return __builtin_bit_cast(float, (u32)u << 16);
}

// ---------------- Kernel 1: QKV projection + BN + ReLU -> bf16 ----------------
// grid (N/128, B, 3), block 256 = 4 waves. Wave g = z*4+w owns 8 channels of one
// of {w1,w2,w3} x 128 n. Weights via uniform s_load; x via float2 vmem.
// q,k -> [B][N][32] bf16 ; v -> [B][32][N] bf16.
__global__ __launch_bounds__(256) void proj_qkv(
    const float* __restrict__ x,
    const float* __restrict__ w1, const float* __restrict__ w2, const float* __restrict__ w3,
    const float* __restrict__ b1s, const float* __restrict__ b1b, const float* __restrict__ b1m, const float* __restrict__ b1v,
    const float* __restrict__ b2s, const float* __restrict__ b2b, const float* __restrict__ b2m, const float* __restrict__ b2v,
    const float* __restrict__ b3s, const float* __restrict__ b3b, const float* __restrict__ b3m, const float* __restrict__ b3v,
    u16* __restrict__ qo, u16* __restrict__ ko, u16* __restrict__ vo)
{
    const int tid  = threadIdx.x;
    const int lane = tid & 63;
    const int b    = blockIdx.y;
    const int g    = __builtin_amdgcn_readfirstlane(blockIdx.z * 4 + (tid >> 6)); // 0..11 uniform
    const int mat  = g >> 2;             // 0:q/w1 1:k/w2 2:v/w3
    const int ch0  = (g & 3) * 8;
    const int n    = blockIdx.x * 128 + lane * 2;

    const float* wb = ((mat == 0) ? w1 : (mat == 1) ? w2 : w3) + (size_t)ch0 * CDIM;

    float2 acc[8];
#pragma unroll
    for (int o = 0; o < 8; ++o) acc[o] = make_float2(0.f, 0.f);

    const float* xb = x + (size_t)b * CDIM * NDIM + n;

#pragma unroll 2
    for (int c = 0; c < CDIM; c += 4) {
        float4 wq[8];
#pragma unroll
        for (int o = 0; o < 8; ++o)
            wq[o] = *reinterpret_cast<const float4*>(wb + o * CDIM + c);  // uniform -> s_load
        float2 xv[4];
#pragma unroll
        for (int cc = 0; cc < 4; ++cc)
            xv[cc] = *reinterpret_cast<const float2*>(xb + (size_t)(c + cc) * NDIM);
#pragma unroll
        for (int cc = 0; cc < 4; ++cc) {
#pragma unroll
            for (int o = 0; o < 8; ++o) {
                float wv = (cc == 0) ? wq[o].x : (cc == 1) ? wq[o].y : (cc == 2) ? wq[o].z : wq[o].w;
                acc[o].x = fmaf(wv, xv[cc].x, acc[o].x);
                acc[o].y = fmaf(wv, xv[cc].y, acc[o].y);
            }
        }
    }

    const float* ps = (mat == 0) ? b1s : (mat == 1) ? b2s : b3s;
    const float* pb = (mat == 0) ? b1b : (mat == 1) ? b2b : b3b;
    const float* pm = (mat == 0) ? b1m : (mat == 1) ? b2m : b3m;
    const float* pv = (mat == 0) ? b1v : (mat == 1) ? b2v : b3v;

    float y0[8], y1[8];
#pragma unroll
    for (int o = 0; o < 8; ++o) {
        float inv = ps[ch0 + o] / sqrtf(pv[ch0 + o] + EPSBN);
        float mb  = pm[ch0 + o];
        float bb  = pb[ch0 + o];
        y0[o] = fmaxf((acc[o].x - mb) * inv + bb, 0.f);
        y1[o] = fmaxf((acc[o].y - mb) * inv + bb, 0.f);
    }

    if (mat < 2) {
        // [B][N][32]: per n, 8 consecutive channels -> one 16B store
        u16* dst = ((mat == 0) ? qo : ko) + ((size_t)b * NDIM + n) * CLD + ch0;
        u32x4 s0, s1;
        s0.x = pack_bf16x2(y0[0], y0[1]); s0.y = pack_bf16x2(y0[2], y0[3]);
        s0.z = pack_bf16x2(y0[4], y0[5]); s0.w = pack_bf16x2(y0[6], y0[7]);
        s1.x = pack_bf16x2(y1[0], y1[1]); s1.y = pack_bf16x2(y1[2], y1[3]);
        s1.z = pack_bf16x2(y1[4], y1[5]); s1.w = pack_bf16x2(y1[6], y1[7]);
        *reinterpret_cast<u32x4*>(dst)       = s0;
        *reinterpret_cast<u32x4*>(dst + CLD) = s1;
    } else {
        // [B][32][N]: per channel, u32 covers (n, n+1) -> coalesced
#pragma unroll
        for (int o = 0; o < 8; ++o)
            *reinterpret_cast<u32*>(vo + ((size_t)b * CLD + ch0 + o) * NDIM + n) = pack_bf16x2(y0[o], y1[o]);
    }
}

// ---------------- Kernel 2: MFMA flash attention with KV split ----------------
// grid (N/128, B, NSPLIT), block 256 = 4 independent waves; wave owns 32 queries.
__global__ __launch_bounds__(256) void attn_mfma(
    const u16* __restrict__ q, const u16* __restrict__ k, const u16* __restrict__ v,
    u16* __restrict__ pO, float* __restrict__ pM, float* __restrict__ pL)
{
    const int tid  = threadIdx.x;
    const int lane = tid & 63;
    const int w    = tid >> 6;
    const int b    = blockIdx.y;
    const int s    = blockIdx.z;
    const int q0   = (blockIdx.x * 4 + w) * 32;
    const int col  = lane & 31;
    const int hi   = lane >> 5;

    const u16* qp = q + ((size_t)b * NDIM + q0 + col) * CLD + 8 * hi;
    bf16x8 qf0 = *reinterpret_cast<const bf16x8*>(qp);
    bf16x8 qf1 = *reinterpret_cast<const bf16x8*>(qp + 16);

    f32x16 o = {0.f,0.f,0.f,0.f, 0.f,0.f,0.f,0.f, 0.f,0.f,0.f,0.f, 0.f,0.f,0.f,0.f};
    float m_run = -3e38f, l_run = 0.f;

    const int kstart = s * KEYS_PER_SPLIT;
    const u16* kb = k + (size_t)b * NDIM * CLD;
    const u16* vb = v + (size_t)b * CLD * NDIM + (size_t)col * NDIM;

    for (int kt = 0; kt < KEYS_PER_SPLIT; kt += 32) {
        const int k0 = kstart + kt;
        const u16* kp = kb + (size_t)(k0 + col) * CLD + 8 * hi;
        bf16x8 kf0 = *reinterpret_cast<const bf16x8*>(kp);
        bf16x8 kf1 = *reinterpret_cast<const bf16x8*>(kp + 16);
        const u16* vp = vb + k0 + 8 * hi;
        bf16x8 vf0 = *reinterpret_cast<const bf16x8*>(vp);
        bf16x8 vf1 = *reinterpret_cast<const bf16x8*>(vp + 16);

        f32x16 sa = {0.f,0.f,0.f,0.f, 0.f,0.f,0.f,0.f, 0.f,0.f,0.f,0.f, 0.f,0.f,0.f,0.f};
        sa = __builtin_amdgcn_mfma_f32_32x32x16_bf16(kf0, qf0, sa, 0, 0, 0);
        sa = __builtin_amdgcn_mfma_f32_32x32x16_bf16(kf1, qf1, sa, 0, 0, 0);

        float tmax = sa[0];
#pragma unroll
        for (int r = 1; r < 16; ++r) tmax = fmaxf(tmax, sa[r]);
        tmax = fmaxf(tmax, __shfl_xor(tmax, 32));
        float mnew = fmaxf(m_run, tmax);
        float f = __expf(m_run - mnew);
        float p[16];
        float psum = 0.f;
#pragma unroll
        for (int r = 0; r < 16; ++r) { p[r] = __expf(sa[r] - mnew); psum += p[r]; }
        psum += __shfl_xor(psum, 32);
        l_run = l_run * f + psum;
        m_run = mnew;
#pragma unroll
        for (int r = 0; r < 16; ++r) o[r] *= f;

        u32 bw[8], bx[8];
#pragma unroll
        for (int t = 0; t < 8; ++t) bw[t] = pack_bf16x2(p[2 * t], p[2 * t + 1]);
#pragma unroll
        for (int t = 0; t < 8; ++t) bx[t] = (u32)__shfl_xor((int)bw[t], 32);

        u32x4 f0u, f1u;
        f0u.x = hi ? bx[2] : bw[0];  f0u.y = hi ? bx[3] : bw[1];
        f0u.z = hi ? bw[2] : bx[0];  f0u.w = hi ? bw[3] : bx[1];
        f1u.x = hi ? bx[6] : bw[4];  f1u.y = hi ? bx[7] : bw[5];
        f1u.z = hi ? bw[6] : bx[4];  f1u.w = hi ? bw[7] : bx[5];
        bf16x8 pf0 = __builtin_bit_cast(bf16x8, f0u);
        bf16x8 pf1 = __builtin_bit_cast(bf16x8, f1u);

        o = __builtin_amdgcn_mfma_f32_32x32x16_bf16(vf0, pf0, o, 0, 0, 0);
        o = __builtin_amdgcn_mfma_f32_32x32x16_bf16(vf1, pf1, o, 0, 0, 0);
    }

    u16* Ob = pO + ((size_t)s * BATCH + b) * CLD * NDIM + q0;
#pragma unroll
    for (int r = 0; r < 16; ++r) {
        int d = (r & 3) + 8 * (r >> 2) + 4 * hi;
        Ob[(size_t)d * NDIM + col] = f2bf(o[r]);
    }
    if (hi == 0) {
        size_t mi = ((size_t)s * BATCH + b) * NDIM + q0 + col;
        pM[mi] = m_run;
        pL[mi] = l_run;
    }
}

// ---------------- Kernel 3: combine + output projection + BN4 + ReLU + residual ----------------
// grid (N/256, B, 8), block 256 = 4 waves. Wave: 8 outputs x 256 n; thread: 8 o x 4 n.
__global__ __launch_bounds__(256) void out_proj(
    const u16* __restrict__ pO, const float* __restrict__ pM, const float* __restrict__ pL,
    const float* __restrict__ wo,
    const float* __restrict__ b4s, const float* __restrict__ b4b,
    const float* __restrict__ b4m, const float* __restrict__ b4v,
    const float* __restrict__ x, const float* __restrict__ gamma,
    float* __restrict__ out)
{
    const int tid   = threadIdx.x;
    const int lane  = tid & 63;
    const int b     = blockIdx.y;
    const int w     = __builtin_amdgcn_readfirstlane(tid >> 6);
    const int obase = blockIdx.z * 32 + w * 8;          // uniform
    const int n     = blockIdx.x * 256 + lane * 4;

    // ---- split-combine weights for this thread's 4 n ----
    float4 mv[NSPLIT], lv[NSPLIT];
#pragma unroll
    for (int s = 0; s < NSPLIT; ++s) {
        mv[s] = *reinterpret_cast<const float4*>(pM + ((size_t)s * BATCH + b) * NDIM + n);
        lv[s] = *reinterpret_cast<const float4*>(pL + ((size_t)s * BATCH + b) * NDIM + n);
    }
    float4 mstar = mv[0];
#pragma unroll
    for (int s = 1; s < NSPLIT; ++s) {
        mstar.x = fmaxf(mstar.x, mv[s].x); mstar.y = fmaxf(mstar.y, mv[s].y);
        mstar.z = fmaxf(mstar.z, mv[s].z); mstar.w = fmaxf(mstar.w, mv[s].w);
    }
    float4 wn[NSPLIT];
    float4 den = make_float4(0.f, 0.f, 0.f, 0.f);
#pragma unroll
    for (int s = 0; s < NSPLIT; ++s) {
        wn[s].x = __expf(mv[s].x - mstar.x); wn[s].y = __expf(mv[s].y - mstar.y);
        wn[s].z = __expf(mv[s].z - mstar.z); wn[s].w = __expf(mv[s].w - mstar.w);
        den.x = fmaf(wn[s].x, lv[s].x, den.x); den.y = fmaf(wn[s].y, lv[s].y, den.y);
        den.z = fmaf(wn[s].z, lv[s].z, den.z); den.w = fmaf(wn[s].w, lv[s].w, den.w);
    }
    den.x = 1.f / den.x; den.y = 1.f / den.y; den.z = 1.f / den.z; den.w = 1.f / den.w;
#pragma unroll
    for (int s = 0; s < NSPLIT; ++s) {
        wn[s].x *= den.x; wn[s].y *= den.y; wn[s].z *= den.z; wn[s].w *= den.w;
    }

    // ---- GEMM: acc[o][nq] over 32 channels, streaming pO ----
    float4 acc[8];
#pragma unroll
    for (int o = 0; o < 8; ++o) acc[o] = make_float4(0.f, 0.f, 0.f, 0.f);

    const float* wbase = wo + (size_t)obase * CLD;      // uniform

#pragma unroll 2
    for (int c = 0; c < CLD; c += 4) {
        float4 wq[8];
#pragma unroll
        for (int o = 0; o < 8; ++o)
            wq[o] = *reinterpret_cast<const float4*>(wbase + o * CLD + c);   // s_load
#pragma unroll
        for (int cc = 0; cc < 4; ++cc) {
            float4 av = make_float4(0.f, 0.f, 0.f, 0.f);
#pragma unroll
            for (int s = 0; s < NSPLIT; ++s) {
                const u16* pp = pO + (((size_t)s * BATCH + b) * CLD + c + cc) * NDIM + n;
                ushort4 uv = *reinterpret_cast<const ushort4*>(pp);
                av.x = fmaf(wn[s].x, bfbits2f(uv.x), av.x);
                av.y = fmaf(wn[s].y, bfbits2f(uv.y), av.y);
                av.z = fmaf(wn[s].z, bfbits2f(uv.z), av.z);
                av.w = fmaf(wn[s].w, bfbits2f(uv.w), av.w);
            }
#pragma unroll
            for (int o = 0; o < 8; ++o) {
                float wv = (cc == 0) ? wq[o].x : (cc == 1) ? wq[o].y : (cc == 2) ? wq[o].z : wq[o].w;
                acc[o].x = fmaf(wv, av.x, acc[o].x);
                acc[o].y = fmaf(wv, av.y, acc[o].y);
                acc[o].z = fmaf(wv, av.z, acc[o].z);
                acc[o].w = fmaf(wv, av.w, acc[o].w);
            }
        }
    }

    const float gm = gamma[0];
#pragma unroll
    for (int o = 0; o < 8; ++o) {
        int oo = obase + o;
        float inv = b4s[oo] / sqrtf(b4v[oo] + EPSBN);
        float bi  = b4b[oo] - b4m[oo] * inv;
        const size_t idx = ((size_t)b * CDIM + oo) * NDIM + n;
        float4 xv = *reinterpret_cast<const float4*>(x + idx);
        float4 r;
        r.x = fmaf(gm, fmaxf(fmaf(acc[o].x, inv, bi), 0.f), xv.x);
        r.y = fmaf(gm, fmaxf(fmaf(acc[o].y, inv, bi), 0.f), xv.y);
        r.z = fmaf(gm, fmaxf(fmaf(acc[o].z, inv, bi), 0.f), xv.z);
        r.w = fmaf(gm, fmaxf(fmaf(acc[o].w, inv, bi), 0.f), xv.w);
        *reinterpret_cast<float4*>(out + idx) = r;
    }
}

extern "C" void kernel_launch(void* const* d_in, const int* in_sizes, int n_in,
                              void* d_out, int out_size, void* d_ws, size_t ws_size,
                              hipStream_t stream) {
    const float* x   = (const float*)d_in[0];
    const float* w1  = (const float*)d_in[1];
    const float* w2  = (const float*)d_in[2];
    const float* w3  = (const float*)d_in[3];
    const float* wo  = (const float*)d_in[4];
    const float* b1s = (const float*)d_in[5];
    const float* b1b = (const float*)d_in[6];
    const float* b1m = (const float*)d_in[7];
    const float* b1v = (const float*)d_in[8];
    const float* b2s = (const float*)d_in[9];
    const float* b2b = (const float*)d_in[10];
    const float* b2m = (const float*)d_in[11];
    const float* b2v = (const float*)d_in[12];
    const float* b3s = (const float*)d_in[13];
    const float* b3b = (const float*)d_in[14];
    const float* b3m = (const float*)d_in[15];
    const float* b3v = (const float*)d_in[16];
    const float* b4s = (const float*)d_in[17];
    const float* b4b = (const float*)d_in[18];
    const float* b4m = (const float*)d_in[19];
    const float* b4v = (const float*)d_in[20];
    const float* gm  = (const float*)d_in[21];
    float* out = (float*)d_out;

    // ws layout (bytes):
    //   [0, 1MB)        : qbf bf16 [B][N][32]
    //   [1MB, 2MB)      : kbf bf16 [B][N][32]
    //   [2MB, 3MB)      : vbf bf16 [B][32][N]
    //   [3MB, 7MB)      : pO  bf16 [S][B][32][N]
    //   [7MB, +256KB)   : pM  f32  [S][B][N]
    //   [7.25MB,+256KB) : pL  f32  [S][B][N]
    char* W = (char*)d_ws;
    u16* qbf = (u16*)W;
    u16* kbf = (u16*)(W + (1u << 20));
    u16* vbf = (u16*)(W + (2u << 20));
    u16* pO  = (u16*)(W + (3u << 20));
    float* pM = (float*)(W + (7u << 20));
    float* pL = (float*)(W + (7u << 20) + (1u << 18));

    dim3 gp(NDIM / 128, BATCH, 3);
    proj_qkv<<<gp, 256, 0, stream>>>(x, w1, w2, w3,
                                     b1s, b1b, b1m, b1v,
                                     b2s, b2b, b2m, b2v,
                                     b3s, b3b, b3m, b3v,
                                     qbf, kbf, vbf);

    dim3 ga(NDIM / 128, BATCH, NSPLIT);
    attn_mfma<<<ga, 256, 0, stream>>>(qbf, kbf, vbf, pO, pM, pL);

    dim3 go(NDIM / 256, BATCH, 8);
    out_proj<<<go, 256, 0, stream>>>(pO, pM, pL, wo, b4s, b4b, b4m, b4v, x, gm, out);
}

// Round 4
// 67.320 us; speedup vs baseline: 5.0020x; 1.1701x over previous
//
#include <hip/hip_runtime.h>
#include <hip/hip_bf16.h>
#include <math.h>

#define BATCH 4
#define CDIM 256
#define NDIM 4096
#define CLD 32
#define EPSBN 1e-5f
#define SPLITS 8
#define KEYS_PER_WAVE (NDIM / SPLITS)   // 512

typedef unsigned short u16;
typedef unsigned int u32;
typedef __attribute__((ext_vector_type(8))) short bf16x8;   // 8 bf16 = 4 VGPR MFMA operand
typedef __attribute__((ext_vector_type(16))) float f32x16;  // 32x32 MFMA accumulator
typedef __attribute__((ext_vector_type(4))) u32 u32x4;

__device__ inline u16 f2bf(float x) {
    return __builtin_bit_cast(u16, __float2bfloat16(x));
}
__device__ inline u32 pack_bf16x2(float a, float b) {
    return (u32)f2bf(a) | ((u32)f2bf(b) << 16);
}

// ---------------- Kernel 1: QKV projection + BN + ReLU -> bf16 ----------------
// grid (N/128, B, 3), block 256 = 4 waves. Wave g = z*4+w owns 8 channels of one
// of {w1,w2,w3} x 128 n. Weights via uniform s_load; x via float2 vmem.
// q,k -> [B][N][32] bf16 ; v -> [B][32][N] bf16.
__global__ __launch_bounds__(256) void proj_qkv(
    const float* __restrict__ x,
    const float* __restrict__ w1, const float* __restrict__ w2, const float* __restrict__ w3,
    const float* __restrict__ b1s, const float* __restrict__ b1b, const float* __restrict__ b1m, const float* __restrict__ b1v,
    const float* __restrict__ b2s, const float* __restrict__ b2b, const float* __restrict__ b2m, const float* __restrict__ b2v,
    const float* __restrict__ b3s, const float* __restrict__ b3b, const float* __restrict__ b3m, const float* __restrict__ b3v,
    u16* __restrict__ qo, u16* __restrict__ ko, u16* __restrict__ vo)
{
    const int tid  = threadIdx.x;
    const int lane = tid & 63;
    const int b    = blockIdx.y;
    const int g    = __builtin_amdgcn_readfirstlane(blockIdx.z * 4 + (tid >> 6)); // 0..11 uniform
    const int mat  = g >> 2;             // 0:q/w1 1:k/w2 2:v/w3
    const int ch0  = (g & 3) * 8;
    const int n    = blockIdx.x * 128 + lane * 2;

    const float* wb = ((mat == 0) ? w1 : (mat == 1) ? w2 : w3) + (size_t)ch0 * CDIM;

    float2 acc[8];
#pragma unroll
    for (int o = 0; o < 8; ++o) acc[o] = make_float2(0.f, 0.f);

    const float* xb = x + (size_t)b * CDIM * NDIM + n;

#pragma unroll 2
    for (int c = 0; c < CDIM; c += 4) {
        float4 wq[8];
#pragma unroll
        for (int o = 0; o < 8; ++o)
            wq[o] = *reinterpret_cast<const float4*>(wb + o * CDIM + c);  // uniform -> s_load
        float2 xv[4];
#pragma unroll
        for (int cc = 0; cc < 4; ++cc)
            xv[cc] = *reinterpret_cast<const float2*>(xb + (size_t)(c + cc) * NDIM);
#pragma unroll
        for (int cc = 0; cc < 4; ++cc) {
#pragma unroll
            for (int o = 0; o < 8; ++o) {
                float wv = (cc == 0) ? wq[o].x : (cc == 1) ? wq[o].y : (cc == 2) ? wq[o].z : wq[o].w;
                acc[o].x = fmaf(wv, xv[cc].x, acc[o].x);
                acc[o].y = fmaf(wv, xv[cc].y, acc[o].y);
            }
        }
    }

    const float* ps = (mat == 0) ? b1s : (mat == 1) ? b2s : b3s;
    const float* pb = (mat == 0) ? b1b : (mat == 1) ? b2b : b3b;
    const float* pm = (mat == 0) ? b1m : (mat == 1) ? b2m : b3m;
    const float* pv = (mat == 0) ? b1v : (mat == 1) ? b2v : b3v;

    float y0[8], y1[8];
#pragma unroll
    for (int o = 0; o < 8; ++o) {
        float inv = ps[ch0 + o] / sqrtf(pv[ch0 + o] + EPSBN);
        float mb  = pm[ch0 + o];
        float bb  = pb[ch0 + o];
        y0[o] = fmaxf((acc[o].x - mb) * inv + bb, 0.f);
        y1[o] = fmaxf((acc[o].y - mb) * inv + bb, 0.f);
    }

    if (mat < 2) {
        u16* dst = ((mat == 0) ? qo : ko) + ((size_t)b * NDIM + n) * CLD + ch0;
        u32x4 s0, s1;
        s0.x = pack_bf16x2(y0[0], y0[1]); s0.y = pack_bf16x2(y0[2], y0[3]);
        s0.z = pack_bf16x2(y0[4], y0[5]); s0.w = pack_bf16x2(y0[6], y0[7]);
        s1.x = pack_bf16x2(y1[0], y1[1]); s1.y = pack_bf16x2(y1[2], y1[3]);
        s1.z = pack_bf16x2(y1[4], y1[5]); s1.w = pack_bf16x2(y1[6], y1[7]);
        *reinterpret_cast<u32x4*>(dst)       = s0;
        *reinterpret_cast<u32x4*>(dst + CLD) = s1;
    } else {
#pragma unroll
        for (int o = 0; o < 8; ++o)
            *reinterpret_cast<u32*>(vo + ((size_t)b * CLD + ch0 + o) * NDIM + n) = pack_bf16x2(y0[o], y1[o]);
    }
}

// p[16] (keys (r&3)+8*(r>>2)+4*hi of a 32-key tile) -> PV B-fragments pf0/pf1
// (frag0: keys 8*hi+i ; frag1: keys 16+8*hi+i). Verified layout (rounds 1-3).
__device__ inline void pack_p(const float* p, int hi, bf16x8& pf0, bf16x8& pf1) {
    u32 bw[8], bx[8];
#pragma unroll
    for (int t = 0; t < 8; ++t) bw[t] = pack_bf16x2(p[2 * t], p[2 * t + 1]);
#pragma unroll
    for (int t = 0; t < 8; ++t) bx[t] = (u32)__shfl_xor((int)bw[t], 32);
    u32x4 f0u, f1u;
    f0u.x = hi ? bx[2] : bw[0];  f0u.y = hi ? bx[3] : bw[1];
    f0u.z = hi ? bw[2] : bx[0];  f0u.w = hi ? bw[3] : bx[1];
    f1u.x = hi ? bx[6] : bw[4];  f1u.y = hi ? bx[7] : bw[5];
    f1u.z = hi ? bw[6] : bx[4];  f1u.w = hi ? bw[7] : bx[5];
    pf0 = __builtin_bit_cast(bf16x8, f0u);
    pf1 = __builtin_bit_cast(bf16x8, f1u);
}

// ---------------- Kernel 2: MFMA flash attention, 8-way split-in-block ----------------
// grid (N/32, B), block 512 = 8 waves; all waves share one 32-query tile, each
// owns 512 keys. LDS combine at the end writes agg f32 [B][32][N] directly.
__global__ __launch_bounds__(512, 4) void attn_mfma(
    const u16* __restrict__ q, const u16* __restrict__ k, const u16* __restrict__ v,
    float* __restrict__ agg)
{
    __shared__ float o_lds[SPLITS][32][32];   // 32 KB
    __shared__ float m_lds[SPLITS][32];
    __shared__ float l_lds[SPLITS][32];

    const int tid  = threadIdx.x;
    const int lane = tid & 63;
    const int w    = tid >> 6;            // split 0..7
    const int b    = blockIdx.y;
    const int q0   = blockIdx.x * 32;
    const int col  = lane & 31;
    const int hi   = lane >> 5;

    const u16* qp = q + ((size_t)b * NDIM + q0 + col) * CLD + 8 * hi;
    bf16x8 qf0 = *reinterpret_cast<const bf16x8*>(qp);
    bf16x8 qf1 = *reinterpret_cast<const bf16x8*>(qp + 16);

    f32x16 o = {0.f,0.f,0.f,0.f, 0.f,0.f,0.f,0.f, 0.f,0.f,0.f,0.f, 0.f,0.f,0.f,0.f};
    float m_run = -3e38f, l_run = 0.f;

    const int kstart = w * KEYS_PER_WAVE;
    const u16* kb = k + (size_t)b * NDIM * CLD;
    const u16* vb = v + (size_t)b * CLD * NDIM + (size_t)col * NDIM;

    for (int kt = 0; kt < KEYS_PER_WAVE; kt += 64) {
        const int k0 = kstart + kt;
        // ---- QK^T for two 32-key tiles (A: k0.., B: k0+32..) ----
        const u16* kpA = kb + (size_t)(k0 + col) * CLD + 8 * hi;
        bf16x8 kfA0 = *reinterpret_cast<const bf16x8*>(kpA);
        bf16x8 kfA1 = *reinterpret_cast<const bf16x8*>(kpA + 16);
        const u16* kpB = kpA + 32 * CLD;
        bf16x8 kfB0 = *reinterpret_cast<const bf16x8*>(kpB);
        bf16x8 kfB1 = *reinterpret_cast<const bf16x8*>(kpB + 16);

        f32x16 sa = {0.f,0.f,0.f,0.f, 0.f,0.f,0.f,0.f, 0.f,0.f,0.f,0.f, 0.f,0.f,0.f,0.f};
        f32x16 sb = {0.f,0.f,0.f,0.f, 0.f,0.f,0.f,0.f, 0.f,0.f,0.f,0.f, 0.f,0.f,0.f,0.f};
        sa = __builtin_amdgcn_mfma_f32_32x32x16_bf16(kfA0, qf0, sa, 0, 0, 0);
        sa = __builtin_amdgcn_mfma_f32_32x32x16_bf16(kfA1, qf1, sa, 0, 0, 0);
        sb = __builtin_amdgcn_mfma_f32_32x32x16_bf16(kfB0, qf0, sb, 0, 0, 0);
        sb = __builtin_amdgcn_mfma_f32_32x32x16_bf16(kfB1, qf1, sb, 0, 0, 0);

        // ---- one softmax pass over 64 keys ----
        float tmax = fmaxf(sa[0], sb[0]);
#pragma unroll
        for (int r = 1; r < 16; ++r) tmax = fmaxf(tmax, fmaxf(sa[r], sb[r]));
        tmax = fmaxf(tmax, __shfl_xor(tmax, 32));
        float mnew = fmaxf(m_run, tmax);
        float f = __expf(m_run - mnew);
        float pa[16], pb[16];
        float psum = 0.f;
#pragma unroll
        for (int r = 0; r < 16; ++r) { pa[r] = __expf(sa[r] - mnew); psum += pa[r]; }
#pragma unroll
        for (int r = 0; r < 16; ++r) { pb[r] = __expf(sb[r] - mnew); psum += pb[r]; }
        psum += __shfl_xor(psum, 32);
        l_run = l_run * f + psum;
        m_run = mnew;
#pragma unroll
        for (int r = 0; r < 16; ++r) o[r] *= f;

        // ---- PV for both tiles ----
        const u16* vp = vb + k0 + 8 * hi;
        bf16x8 vfA0 = *reinterpret_cast<const bf16x8*>(vp);
        bf16x8 vfA1 = *reinterpret_cast<const bf16x8*>(vp + 16);
        bf16x8 vfB0 = *reinterpret_cast<const bf16x8*>(vp + 32);
        bf16x8 vfB1 = *reinterpret_cast<const bf16x8*>(vp + 48);

        bf16x8 pf0, pf1;
        pack_p(pa, hi, pf0, pf1);
        o = __builtin_amdgcn_mfma_f32_32x32x16_bf16(vfA0, pf0, o, 0, 0, 0);
        o = __builtin_amdgcn_mfma_f32_32x32x16_bf16(vfA1, pf1, o, 0, 0, 0);
        pack_p(pb, hi, pf0, pf1);
        o = __builtin_amdgcn_mfma_f32_32x32x16_bf16(vfB0, pf0, o, 0, 0, 0);
        o = __builtin_amdgcn_mfma_f32_32x32x16_bf16(vfB1, pf1, o, 0, 0, 0);
    }

    // ---- publish partials ----
#pragma unroll
    for (int r = 0; r < 16; ++r) {
        int d = (r & 3) + 8 * (r >> 2) + 4 * hi;
        o_lds[w][d][col] = o[r];
    }
    if (hi == 0) { m_lds[w][col] = m_run; l_lds[w][col] = l_run; }
    __syncthreads();

    // ---- combine 8 splits: thread -> q=tid&31, d in {tid>>5, tid>>5 + 16} ----
    {
        const int qq = tid & 31;
        const int d0 = tid >> 5;          // 0..15
        float ms[SPLITS];
        float mstar = -3e38f;
#pragma unroll
        for (int s = 0; s < SPLITS; ++s) { ms[s] = m_lds[s][qq]; mstar = fmaxf(mstar, ms[s]); }
        float wn[SPLITS];
        float den = 0.f;
#pragma unroll
        for (int s = 0; s < SPLITS; ++s) {
            wn[s] = __expf(ms[s] - mstar);
            den = fmaf(wn[s], l_lds[s][qq], den);
        }
        float inv = 1.f / den;
#pragma unroll
        for (int s = 0; s < SPLITS; ++s) wn[s] *= inv;
#pragma unroll
        for (int dd = 0; dd < 2; ++dd) {
            int d = d0 + 16 * dd;
            float a2 = 0.f;
#pragma unroll
            for (int s = 0; s < SPLITS; ++s) a2 = fmaf(wn[s], o_lds[s][d][qq], a2);
            agg[((size_t)b * CLD + d) * NDIM + q0 + qq] = a2;
        }
    }
}

// ---------------- Kernel 3: output projection + BN4 + ReLU + residual ----------------
// grid (N/256, B, 8), block 256 = 4 waves. Wave: 8 outputs x 256 n; thread: 8 o x 4 n.
__global__ __launch_bounds__(256) void out_proj(
    const float* __restrict__ agg, const float* __restrict__ wo,
    const float* __restrict__ b4s, const float* __restrict__ b4b,
    const float* __restrict__ b4m, const float* __restrict__ b4v,
    const float* __restrict__ x, const float* __restrict__ gamma,
    float* __restrict__ out)
{
    const int tid   = threadIdx.x;
    const int lane  = tid & 63;
    const int b     = blockIdx.y;
    const int w     = __builtin_amdgcn_readfirstlane(tid >> 6);
    const int obase = blockIdx.z * 32 + w * 8;          // uniform
    const int n     = blockIdx.x * 256 + lane * 4;

    float4 acc[8];
#pragma unroll
    for (int o = 0; o < 8; ++o) acc[o] = make_float4(0.f, 0.f, 0.f, 0.f);

    const float* wbase = wo + (size_t)obase * CLD;      // uniform

#pragma unroll 2
    for (int c = 0; c < CLD; c += 4) {
        float4 wq[8];
#pragma unroll
        for (int o = 0; o < 8; ++o)
            wq[o] = *reinterpret_cast<const float4*>(wbase + o * CLD + c);   // s_load
        float4 av[4];
#pragma unroll
        for (int cc = 0; cc < 4; ++cc)
            av[cc] = *reinterpret_cast<const float4*>(agg + ((size_t)b * CLD + c + cc) * NDIM + n);
#pragma unroll
        for (int cc = 0; cc < 4; ++cc) {
#pragma unroll
            for (int o = 0; o < 8; ++o) {
                float wv = (cc == 0) ? wq[o].x : (cc == 1) ? wq[o].y : (cc == 2) ? wq[o].z : wq[o].w;
                acc[o].x = fmaf(wv, av[cc].x, acc[o].x);
                acc[o].y = fmaf(wv, av[cc].y, acc[o].y);
                acc[o].z = fmaf(wv, av[cc].z, acc[o].z);
                acc[o].w = fmaf(wv, av[cc].w, acc[o].w);
            }
        }
    }

    const float gm = gamma[0];
#pragma unroll
    for (int o = 0; o < 8; ++o) {
        int oo = obase + o;
        float inv = b4s[oo] / sqrtf(b4v[oo] + EPSBN);
        float bi  = b4b[oo] - b4m[oo] * inv;
        const size_t idx = ((size_t)b * CDIM + oo) * NDIM + n;
        float4 xv = *reinterpret_cast<const float4*>(x + idx);
        float4 r;
        r.x = fmaf(gm, fmaxf(fmaf(acc[o].x, inv, bi), 0.f), xv.x);
        r.y = fmaf(gm, fmaxf(fmaf(acc[o].y, inv, bi), 0.f), xv.y);
        r.z = fmaf(gm, fmaxf(fmaf(acc[o].z, inv, bi), 0.f), xv.z);
        r.w = fmaf(gm, fmaxf(fmaf(acc[o].w, inv, bi), 0.f), xv.w);
        *reinterpret_cast<float4*>(out + idx) = r;
    }
}

extern "C" void kernel_launch(void* const* d_in, const int* in_sizes, int n_in,
                              void* d_out, int out_size, void* d_ws, size_t ws_size,
                              hipStream_t stream) {
    const float* x   = (const float*)d_in[0];
    const float* w1  = (const float*)d_in[1];
    const float* w2  = (const float*)d_in[2];
    const float* w3  = (const float*)d_in[3];
    const float* wo  = (const float*)d_in[4];
    const float* b1s = (const float*)d_in[5];
    const float* b1b = (const float*)d_in[6];
    const float* b1m = (const float*)d_in[7];
    const float* b1v = (const float*)d_in[8];
    const float* b2s = (const float*)d_in[9];
    const float* b2b = (const float*)d_in[10];
    const float* b2m = (const float*)d_in[11];
    const float* b2v = (const float*)d_in[12];
    const float* b3s = (const float*)d_in[13];
    const float* b3b = (const float*)d_in[14];
    const float* b3m = (const float*)d_in[15];
    const float* b3v = (const float*)d_in[16];
    const float* b4s = (const float*)d_in[17];
    const float* b4b = (const float*)d_in[18];
    const float* b4m = (const float*)d_in[19];
    const float* b4v = (const float*)d_in[20];
    const float* gm  = (const float*)d_in[21];
    float* out = (float*)d_out;

    // ws layout (bytes):
    //   [0, 1MB)   : qbf bf16 [B][N][32]
    //   [1MB, 2MB) : kbf bf16 [B][N][32]
    //   [2MB, 3MB) : vbf bf16 [B][32][N]
    //   [3MB, 5MB) : agg f32  [B][32][N]
    char* W = (char*)d_ws;
    u16* qbf = (u16*)W;
    u16* kbf = (u16*)(W + (1u << 20));
    u16* vbf = (u16*)(W + (2u << 20));
    float* agg = (float*)(W + (3u << 20));

    dim3 gp(NDIM / 128, BATCH, 3);
    proj_qkv<<<gp, 256, 0, stream>>>(x, w1, w2, w3,
                                     b1s, b1b, b1m, b1v,
                                     b2s, b2b, b2m, b2v,
                                     b3s, b3b, b3m, b3v,
                                     qbf, kbf, vbf);

    dim3 ga(NDIM / 32, BATCH);
    attn_mfma<<<ga, 512, 0, stream>>>(qbf, kbf, vbf, agg);

    dim3 go(NDIM / 256, BATCH, 8);
    out_proj<<<go, 256, 0, stream>>>(agg, wo, b4s, b4b, b4m, b4v, x, gm, out);
}